// Round 9
// baseline (57.297 us; speedup 1.0000x reference)
//
#include <hip/hip_runtime.h>
#include <hip/hip_bf16.h>

#define MIN_PTS 4

typedef short bf16x8 __attribute__((ext_vector_type(8)));
typedef float f32x4  __attribute__((ext_vector_type(4)));

__device__ __forceinline__ ushort f2bf(float x) {
    unsigned u = __float_as_uint(x);
    u = (u + 0x7fffu + ((u >> 16) & 1u)) >> 16;   // RNE, finite inputs
    return (ushort)u;
}

// v_cvt_pk_bf16_f32: lo -> low 16, hi -> high 16 (RNE)
__device__ __forceinline__ uint cvt_pk_bf16(float lo, float hi) {
    union { __hip_bfloat162 h; uint u; } cv;
    cv.h = __float22bfloat162_rn(make_float2(lo, hi));
    return cv.u;
}

// Pack W2 [64][128] and W3 [128][256] (fp32 row-major, K x N) into bf16
// MFMA B-fragment-linear layout: [ntile][kstep][lane][8], where
// element j of lane l = W[k = 32*ks + 8*(l>>4) + j][col = 16*nt + (l&15)].
// Also zeroes featsG (saves a separate memset launch).
__global__ void pack_zero(const float* __restrict__ W2, const float* __restrict__ W3,
                          ushort* __restrict__ B2P, ushort* __restrict__ B3P,
                          int* __restrict__ featsG, int PF)
{
    int idx = blockIdx.x * 256 + threadIdx.x;
    if (idx < 8192) {   // W2: 8 ntiles x 2 ksteps x 64 lanes x 8
        int j = idx & 7, l = (idx >> 3) & 63, ks = (idx >> 9) & 1, nt = idx >> 10;
        int k   = ks * 32 + (l >> 4) * 8 + j;
        int col = nt * 16 + (l & 15);
        B2P[idx] = f2bf(W2[k * 128 + col]);
    }
    if (idx < 32768) {  // W3: 16 ntiles x 4 ksteps x 64 lanes x 8
        int j = idx & 7, l = (idx >> 3) & 63, ks = (idx >> 9) & 3, nt = idx >> 11;
        int k   = ks * 32 + (l >> 4) * 8 + j;
        int col = nt * 16 + (l & 15);
        B3P[idx] = f2bf(W3[k * 256 + col]);
    }
    if (idx < PF) featsG[idx] = 0;
}

// One block (8 waves, 512 thr) = TWO 64-point stripes of one proposal,
// software-pipelined: A(s0) | bar | A(s1)+B(s0) | bar | B(s1)+D(s0) | bar | D(s1).
// Wave w: layer1 feats 8w..8w+7; layer2 ntile w; layer3 ntiles {2w, 2w+1}.
__global__ __launch_bounds__(512, 4) void refine_pair(
    const float* __restrict__ points,    // [P][N][3]
    const int*   __restrict__ lengths,   // [P]
    const float* __restrict__ proposals, // [P][6]
    const float* __restrict__ W1, const float* __restrict__ b1,   // [3][64],[64]
    const float* __restrict__ b2,                                  // [128]
    const float* __restrict__ b3,                                  // [256]
    const ushort* __restrict__ B2P, const ushort* __restrict__ B3P,
    int* __restrict__ featsG,            // [P][256] f32 bits, pre-zeroed
    int P, int N)
{
    const int bid  = blockIdx.x;
    const int p    = bid >> 1;
    const int s0   = (bid & 1) * 2;
    const int len  = lengths[p];
    if (len < MIN_PTS || s0 * 64 >= len) return;   // feats stay 0 -> bias-only heads
    const bool act1 = (s0 + 1) * 64 < len;

    __shared__ __align__(16) ushort A1[2][4096];   // [buf][mt(4)][ks(2)][lane][8] = 2x8 KB
    __shared__ __align__(16) ushort A3[2][8192];   // [buf][mt(4)][ks(4)][lane][8] = 2x16 KB

    const int tid  = threadIdx.x;
    const int lane = tid & 63;
    const int wu   = __builtin_amdgcn_readfirstlane(tid >> 6);  // wave id 0..7
    const int rc   = lane & 15;
    const int g    = lane >> 4;

    // proposal params (block-uniform -> scalar)
    const float cx = proposals[p * 6 + 0];
    const float cy = proposals[p * 6 + 1];
    const float cz = proposals[p * 6 + 2];
    const float rx = __builtin_amdgcn_rcpf(fmaf(proposals[p * 6 + 3], 0.5f, 1e-6f));
    const float ry = __builtin_amdgcn_rcpf(fmaf(proposals[p * 6 + 4], 0.5f, 1e-6f));
    const float rz = __builtin_amdgcn_rcpf(fmaf(proposals[p * 6 + 5], 0.5f, 1e-6f));

    // layer-1 weights: wave-uniform -> scalar loads, SGPR-resident
    float w1a[8], w1b[8], w1c[8], b1r[8];
    #pragma unroll
    for (int i = 0; i < 8; ++i) {
        const int f = wu * 8 + i;
        w1a[i] = W1[f]; w1b[i] = W1[64 + f]; w1c[i] = W1[128 + f]; b1r[i] = b1[f];
    }
    // per-lane biases (folded into MFMA C-init)
    f32x4 bias2q;
    #pragma unroll
    for (int rr = 0; rr < 4; ++rr) bias2q[rr] = b2[16 * wu + 4 * g + rr];
    const float b3v0 = b3[16 * (2 * wu + 0) + rc];
    const float b3v1 = b3[16 * (2 * wu + 1) + rc];

    // iteration-invariant A1 write slot: k0 = 8w -> ks = w>>2, g2 = w&3
    const int a1chunk = ((lane >> 4) * 2 + (wu >> 2)) * 64 + (wu & 3) * 16 + rc;
    const int ks3 = wu >> 1;                 // (16w+4g)>>5
    const int g3  = (2 * wu + (g >> 1)) & 3; // ((16w+4g)>>3)&3

    // ---------- Phase A: layer 1 (3->64), one uint4 LDS write/lane ----------
    auto phaseA = [&](int s, int buf) {
        const int jj = min(s * 64 + lane, len - 1);     // duplicate last point (max-safe)
        const float* pt = points + ((long)p * N + jj) * 3;
        const float x0 = (pt[0] - cx) * rx;
        const float x1 = (pt[1] - cy) * ry;
        const float x2 = (pt[2] - cz) * rz;
        float v[8];
        #pragma unroll
        for (int i = 0; i < 8; ++i)
            v[i] = fmaxf(fmaf(x0, w1a[i], fmaf(x1, w1b[i], fmaf(x2, w1c[i], b1r[i]))), 0.f);
        uint4 qq;
        qq.x = cvt_pk_bf16(v[0], v[1]);
        qq.y = cvt_pk_bf16(v[2], v[3]);
        qq.z = cvt_pk_bf16(v[4], v[5]);
        qq.w = cvt_pk_bf16(v[6], v[7]);
        *(uint4*)&A1[buf][a1chunk * 8] = qq;
    };

    // ---------- Phase B: layer 2 (64->128), swapped operands, ntile = w ----------
    auto phaseB = [&](int buf) {
        f32x4 acc2[4];
        #pragma unroll
        for (int mt = 0; mt < 4; ++mt) acc2[mt] = bias2q;   // bias folded
        #pragma unroll
        for (int ks = 0; ks < 2; ++ks) {
            const bf16x8 bw = *(const bf16x8*)(B2P + ((wu * 2 + ks) * 64 + lane) * 8);
            #pragma unroll
            for (int mt = 0; mt < 4; ++mt) {
                const bf16x8 a = *(const bf16x8*)&A1[buf][((mt * 2 + ks) * 64 + lane) * 8];
                acc2[mt] = __builtin_amdgcn_mfma_f32_16x16x32_bf16(bw, a, acc2[mt], 0, 0, 0);
            }
        }
        // relu + pack 4 consecutive layer-3 k's of one point -> ds_write_b64
        #pragma unroll
        for (int mt = 0; mt < 4; ++mt) {
            const uint u0 = cvt_pk_bf16(fmaxf(acc2[mt][0], 0.f), fmaxf(acc2[mt][1], 0.f));
            const uint u1 = cvt_pk_bf16(fmaxf(acc2[mt][2], 0.f), fmaxf(acc2[mt][3], 0.f));
            const int chunk = (mt * 4 + ks3) * 64 + g3 * 16 + rc;
            uint2 val; val.x = u0; val.y = u1;
            *(uint2*)&A3[buf][chunk * 8 + (g & 1) * 4] = val;
        }
    };

    // ---------- Phase D: layer 3 (128->256), ntiles {2w,2w+1}, fused pool ----------
    auto phaseD = [&](int buf) {
        f32x4 acc3a[4], acc3b[4];
        #pragma unroll
        for (int mt = 0; mt < 4; ++mt) {
            acc3a[mt] = (f32x4){b3v0, b3v0, b3v0, b3v0};    // bias folded
            acc3b[mt] = (f32x4){b3v1, b3v1, b3v1, b3v1};
        }
        #pragma unroll
        for (int ks = 0; ks < 4; ++ks) {
            const bf16x8 bf0 = *(const bf16x8*)(B3P + (((2 * wu + 0) * 4 + ks) * 64 + lane) * 8);
            const bf16x8 bf1 = *(const bf16x8*)(B3P + (((2 * wu + 1) * 4 + ks) * 64 + lane) * 8);
            #pragma unroll
            for (int mt = 0; mt < 4; ++mt) {
                const bf16x8 a = *(const bf16x8*)&A3[buf][((mt * 4 + ks) * 64 + lane) * 8];
                acc3a[mt] = __builtin_amdgcn_mfma_f32_16x16x32_bf16(a, bf0, acc3a[mt], 0, 0, 0);
                acc3b[mt] = __builtin_amdgcn_mfma_f32_16x16x32_bf16(a, bf1, acc3b[mt], 0, 0, 0);
            }
        }
        float pool0 = 0.f, pool1 = 0.f;   // relu folded into 0-init
        #pragma unroll
        for (int mt = 0; mt < 4; ++mt)
            #pragma unroll
            for (int rr = 0; rr < 4; ++rr) {
                pool0 = fmaxf(pool0, acc3a[mt][rr]);
                pool1 = fmaxf(pool1, acc3b[mt][rr]);
            }
        pool0 = fmaxf(pool0, __shfl_xor(pool0, 16, 64));
        pool0 = fmaxf(pool0, __shfl_xor(pool0, 32, 64));
        pool1 = fmaxf(pool1, __shfl_xor(pool1, 16, 64));
        pool1 = fmaxf(pool1, __shfl_xor(pool1, 32, 64));
        if (g == 0) {
            atomicMax(&featsG[p * 256 + (2 * wu + 0) * 16 + rc], __float_as_int(pool0));
            atomicMax(&featsG[p * 256 + (2 * wu + 1) * 16 + rc], __float_as_int(pool1));
        }
    };

    // ---------- pipelined schedule ----------
    phaseA(s0, 0);
    __syncthreads();

    if (act1) phaseA(s0 + 1, 1);    // global loads + VALU hide under B(s0) MFMAs
    phaseB(0);
    __syncthreads();

    if (act1) phaseB(1);            // MFMAs overlap D(s0) epilogue VALU
    phaseD(0);
    __syncthreads();

    if (act1) phaseD(1);
}

// One wave per proposal: 5 dot products of length 256.
__global__ __launch_bounds__(256) void heads_kernel(
    const int* __restrict__ featsG,
    const float* __restrict__ Wc, const float* __restrict__ bc,
    const float* __restrict__ Wr, const float* __restrict__ br,
    float* __restrict__ out, int P)
{
    const int tid  = threadIdx.x;
    const int lane = tid & 63;
    const int p    = blockIdx.x * 4 + (tid >> 6);
    if (p >= P) return;

    const int4 vi = *(const int4*)&featsG[p * 256 + lane * 4];
    float v[4] = {__int_as_float(vi.x), __int_as_float(vi.y),
                  __int_as_float(vi.z), __int_as_float(vi.w)};

    const float4 wc = *(const float4*)&Wc[lane * 4];
    float c  = v[0] * wc.x + v[1] * wc.y + v[2] * wc.z + v[3] * wc.w;
    float r0 = 0.f, r1 = 0.f, r2 = 0.f, r3 = 0.f;
    #pragma unroll
    for (int i = 0; i < 4; ++i) {
        const float4 wr = *(const float4*)&Wr[(lane * 4 + i) * 4];
        r0 = fmaf(v[i], wr.x, r0);
        r1 = fmaf(v[i], wr.y, r1);
        r2 = fmaf(v[i], wr.z, r2);
        r3 = fmaf(v[i], wr.w, r3);
    }
    #pragma unroll
    for (int off = 32; off > 0; off >>= 1) {
        c  += __shfl_xor(c,  off, 64);
        r0 += __shfl_xor(r0, off, 64);
        r1 += __shfl_xor(r1, off, 64);
        r2 += __shfl_xor(r2, off, 64);
        r3 += __shfl_xor(r3, off, 64);
    }
    if (lane == 0) {
        out[p]             = c  + bc[0];
        out[P + p * 4 + 0] = r0 + br[0];
        out[P + p * 4 + 1] = r1 + br[1];
        out[P + p * 4 + 2] = r2 + br[2];
        out[P + p * 4 + 3] = r3 + br[3];
    }
}

extern "C" void kernel_launch(void* const* d_in, const int* in_sizes, int n_in,
                              void* d_out, int out_size, void* d_ws, size_t ws_size,
                              hipStream_t stream)
{
    const float* points    = (const float*)d_in[0];
    const int*   lengths   = (const int*)  d_in[1];
    const float* proposals = (const float*)d_in[2];
    const float* W1 = (const float*)d_in[3];
    const float* b1 = (const float*)d_in[4];
    const float* W2 = (const float*)d_in[5];
    const float* b2 = (const float*)d_in[6];
    const float* W3 = (const float*)d_in[7];
    const float* b3 = (const float*)d_in[8];
    const float* Wc = (const float*)d_in[9];
    const float* bc = (const float*)d_in[10];
    const float* Wr = (const float*)d_in[11];
    const float* br = (const float*)d_in[12];
    float* out = (float*)d_out;

    const int P = in_sizes[1];              // 2048
    const int N = in_sizes[0] / (3 * P);    // 256
    const int PAIRS = ((N + 63) / 64 + 1) / 2;  // 2 stripe-pairs (4 stripes)

    ushort* B2P    = (ushort*)d_ws;                 // 8192 bf16  (16 KB)
    ushort* B3P    = B2P + 8192;                    // 32768 bf16 (64 KB)
    int*    featsG = (int*)((char*)d_ws + 81920);   // P*256 ints (2 MB)

    const int PF = P * 256;
    pack_zero<<<dim3((PF + 255) / 256), dim3(256), 0, stream>>>(
        W2, W3, B2P, B3P, featsG, PF);
    refine_pair<<<dim3(P * PAIRS), dim3(512), 0, stream>>>(
        points, lengths, proposals, W1, b1, b2, b3, B2P, B3P, featsG, P, N);
    heads_kernel<<<dim3((P + 3) / 4), dim3(256), 0, stream>>>(
        featsG, Wc, bc, Wr, br, out, P);
}

// Round 10
// 54.278 us; speedup vs baseline: 1.0556x; 1.0556x over previous
//
#include <hip/hip_runtime.h>
#include <hip/hip_bf16.h>

#define MIN_PTS 4

typedef short bf16x8 __attribute__((ext_vector_type(8)));
typedef float f32x4  __attribute__((ext_vector_type(4)));

__device__ __forceinline__ ushort f2bf(float x) {
    unsigned u = __float_as_uint(x);
    u = (u + 0x7fffu + ((u >> 16) & 1u)) >> 16;   // RNE, finite inputs
    return (ushort)u;
}

// v_cvt_pk_bf16_f32: lo -> low 16, hi -> high 16 (RNE)
__device__ __forceinline__ uint cvt_pk_bf16(float lo, float hi) {
    union { __hip_bfloat162 h; uint u; } cv;
    cv.h = __float22bfloat162_rn(make_float2(lo, hi));
    return cv.u;
}

// B2P: W2 [64][128] -> bf16 A-operand fragments (W2^T), [nt(8)][ks(2)][lane][8]:
//   elem j of lane l = W2[k = 32ks + 8(l>>4) + j][feat = 16nt + (l&15)]   (unchanged)
// B3P: W3 [128][256] -> bf16 B-operand fragments with PSI-PERMUTED k-rows,
//   [nt(16)][ks(4)][lane][8]:
//   elem j of lane l = W3[psi][col = 16nt + (l&15)],
//   psi = 32ks + 16*(j>>2) + 4*(l>>4) + (j&3)
// psi makes the layer2->layer3 fragment handoff lane-local (no LDS/shuffle).
__global__ void pack_weights(const float* __restrict__ W2, const float* __restrict__ W3,
                             ushort* __restrict__ B2P, ushort* __restrict__ B3P)
{
    int idx = blockIdx.x * 256 + threadIdx.x;
    if (idx < 8192) {   // W2: 8 ntiles x 2 ksteps x 64 lanes x 8
        int j = idx & 7, l = (idx >> 3) & 63, ks = (idx >> 9) & 1, nt = idx >> 10;
        int k   = ks * 32 + (l >> 4) * 8 + j;
        int col = nt * 16 + (l & 15);
        B2P[idx] = f2bf(W2[k * 128 + col]);
    }
    if (idx < 32768) {  // W3: 16 ntiles x 4 ksteps x 64 lanes x 8, psi rows
        int j = idx & 7, l = (idx >> 3) & 63, ks = (idx >> 9) & 3, nt = idx >> 11;
        int k   = 32 * ks + 16 * (j >> 2) + 4 * (l >> 4) + (j & 3);   // psi
        int col = nt * 16 + (l & 15);
        B3P[idx] = f2bf(W3[k * 256 + col]);
    }
}

// Barrier-free, LDS-free: one WAVE = one 64-point stripe, whole MLP in-register.
// Block = 4 waves = stripes 0..3 of proposal blockIdx.x; wave s exits if
// s*64 >= len. Lane (g=lane>>4, rc=lane&15) owns point 16mt+rc (mt=0..3).
__global__ __launch_bounds__(256, 3) void refine_wave(
    const float* __restrict__ points,    // [P][N][3]
    const int*   __restrict__ lengths,   // [P]
    const float* __restrict__ proposals, // [P][6]
    const float* __restrict__ W1, const float* __restrict__ b1,   // [3][64],[64]
    const float* __restrict__ b2,                                  // [128]
    const float* __restrict__ b3,                                  // [256]
    const ushort* __restrict__ B2P, const ushort* __restrict__ B3P,
    int* __restrict__ featsG,            // [P][256] f32 bits, pre-zeroed
    int P, int N)
{
    const int p   = blockIdx.x;
    const int len = lengths[p];
    if (len < MIN_PTS) return;                     // feats stay 0 -> bias-only heads

    const int tid  = threadIdx.x;
    const int s    = __builtin_amdgcn_readfirstlane(tid >> 6);  // stripe = wave id
    if (s * 64 >= len) return;                     // wave-uniform exit, no barriers

    const int lane = tid & 63;
    const int rc   = lane & 15;
    const int g    = lane >> 4;

    // proposal params (block-uniform -> scalar)
    const float cx = proposals[p * 6 + 0];
    const float cy = proposals[p * 6 + 1];
    const float cz = proposals[p * 6 + 2];
    const float rx = __builtin_amdgcn_rcpf(fmaf(proposals[p * 6 + 3], 0.5f, 1e-6f));
    const float ry = __builtin_amdgcn_rcpf(fmaf(proposals[p * 6 + 4], 0.5f, 1e-6f));
    const float rz = __builtin_amdgcn_rcpf(fmaf(proposals[p * 6 + 5], 0.5f, 1e-6f));

    union U16 { uint u[4]; bf16x8 v; };

    // ---------- Phase A: layer 1 (3->64), h1 built directly in A-frag layout ----------
    // lane (g,rc) computes h1[k = 32ka + 8g + j][pt = 16mt + rc] itself.
    U16 a1[4][2];   // [mt][ka]
    {
        f32x4 wA[2][2], wB[2][2], wC[2][2], bV[2][2];   // [ka][half], L1-broadcast loads
        #pragma unroll
        for (int ka = 0; ka < 2; ++ka) {
            const int fb = 32 * ka + 8 * g;
            wA[ka][0] = *(const f32x4*)&W1[fb];        wA[ka][1] = *(const f32x4*)&W1[fb + 4];
            wB[ka][0] = *(const f32x4*)&W1[64 + fb];   wB[ka][1] = *(const f32x4*)&W1[64 + fb + 4];
            wC[ka][0] = *(const f32x4*)&W1[128 + fb];  wC[ka][1] = *(const f32x4*)&W1[128 + fb + 4];
            bV[ka][0] = *(const f32x4*)&b1[fb];        bV[ka][1] = *(const f32x4*)&b1[fb + 4];
        }
        const long pb = (long)p * N;
        #pragma unroll
        for (int mt = 0; mt < 4; ++mt) {
            const int jj = min(s * 64 + mt * 16 + rc, len - 1);   // dup last point (max-safe)
            const float* pt = points + (pb + jj) * 3;
            const float x0 = (pt[0] - cx) * rx;
            const float x1 = (pt[1] - cy) * ry;
            const float x2 = (pt[2] - cz) * rz;
            #pragma unroll
            for (int ka = 0; ka < 2; ++ka) {
                #pragma unroll
                for (int h = 0; h < 2; ++h) {
                    float v0 = fmaxf(fmaf(x0, wA[ka][h][0], fmaf(x1, wB[ka][h][0], fmaf(x2, wC[ka][h][0], bV[ka][h][0]))), 0.f);
                    float v1 = fmaxf(fmaf(x0, wA[ka][h][1], fmaf(x1, wB[ka][h][1], fmaf(x2, wC[ka][h][1], bV[ka][h][1]))), 0.f);
                    float v2 = fmaxf(fmaf(x0, wA[ka][h][2], fmaf(x1, wB[ka][h][2], fmaf(x2, wC[ka][h][2], bV[ka][h][2]))), 0.f);
                    float v3 = fmaxf(fmaf(x0, wA[ka][h][3], fmaf(x1, wB[ka][h][3], fmaf(x2, wC[ka][h][3], bV[ka][h][3]))), 0.f);
                    a1[mt][ka].u[2 * h + 0] = cvt_pk_bf16(v0, v1);
                    a1[mt][ka].u[2 * h + 1] = cvt_pk_bf16(v2, v3);
                }
            }
        }
    }

    // ---------- Phase B: layer 2 (64->128), swapped operands, all 8 ntiles ----------
    // chunk ks3 covers nt {2ks3, 2ks3+1}; psi-packing makes pa lane-local.
    U16 pa[4][4];   // [ks3][mt] : layer-3 A-fragments
    #pragma unroll
    for (int ks3 = 0; ks3 < 4; ++ks3) {
        f32x4 acc[2][4];   // [nt][mt]
        #pragma unroll
        for (int n = 0; n < 2; ++n) {
            const f32x4 bq = *(const f32x4*)&b2[16 * (2 * ks3 + n) + 4 * g];
            #pragma unroll
            for (int mt = 0; mt < 4; ++mt) acc[n][mt] = bq;        // bias folded
        }
        #pragma unroll
        for (int kb = 0; kb < 2; ++kb) {
            const bf16x8 bw0 = *(const bf16x8*)(B2P + (((2 * ks3 + 0) * 2 + kb) * 64 + lane) * 8);
            const bf16x8 bw1 = *(const bf16x8*)(B2P + (((2 * ks3 + 1) * 2 + kb) * 64 + lane) * 8);
            #pragma unroll
            for (int mt = 0; mt < 4; ++mt) {
                acc[0][mt] = __builtin_amdgcn_mfma_f32_16x16x32_bf16(bw0, a1[mt][kb].v, acc[0][mt], 0, 0, 0);
                acc[1][mt] = __builtin_amdgcn_mfma_f32_16x16x32_bf16(bw1, a1[mt][kb].v, acc[1][mt], 0, 0, 0);
            }
        }
        #pragma unroll
        for (int mt = 0; mt < 4; ++mt) {   // relu + pack: pure lane-local (psi)
            pa[ks3][mt].u[0] = cvt_pk_bf16(fmaxf(acc[0][mt][0], 0.f), fmaxf(acc[0][mt][1], 0.f));
            pa[ks3][mt].u[1] = cvt_pk_bf16(fmaxf(acc[0][mt][2], 0.f), fmaxf(acc[0][mt][3], 0.f));
            pa[ks3][mt].u[2] = cvt_pk_bf16(fmaxf(acc[1][mt][0], 0.f), fmaxf(acc[1][mt][1], 0.f));
            pa[ks3][mt].u[3] = cvt_pk_bf16(fmaxf(acc[1][mt][2], 0.f), fmaxf(acc[1][mt][3], 0.f));
        }
    }

    // ---------- Phase D: layer 3 (128->256), 8 chunks of 2 ntiles, fused pool ----------
    #pragma unroll 2
    for (int c = 0; c < 8; ++c) {
        const int nt0 = 2 * c, nt1 = 2 * c + 1;
        const float bv0 = b3[16 * nt0 + rc];
        const float bv1 = b3[16 * nt1 + rc];
        f32x4 acc[2][4];
        #pragma unroll
        for (int mt = 0; mt < 4; ++mt) {
            acc[0][mt] = (f32x4){bv0, bv0, bv0, bv0};   // bias folded
            acc[1][mt] = (f32x4){bv1, bv1, bv1, bv1};
        }
        #pragma unroll
        for (int ks = 0; ks < 4; ++ks) {
            const bf16x8 f0 = *(const bf16x8*)(B3P + ((nt0 * 4 + ks) * 64 + lane) * 8);
            const bf16x8 f1 = *(const bf16x8*)(B3P + ((nt1 * 4 + ks) * 64 + lane) * 8);
            #pragma unroll
            for (int mt = 0; mt < 4; ++mt) {
                acc[0][mt] = __builtin_amdgcn_mfma_f32_16x16x32_bf16(pa[ks][mt].v, f0, acc[0][mt], 0, 0, 0);
                acc[1][mt] = __builtin_amdgcn_mfma_f32_16x16x32_bf16(pa[ks][mt].v, f1, acc[1][mt], 0, 0, 0);
            }
        }
        float p0 = 0.f, p1 = 0.f;   // relu folded into 0-init
        #pragma unroll
        for (int mt = 0; mt < 4; ++mt)
            #pragma unroll
            for (int rr = 0; rr < 4; ++rr) {
                p0 = fmaxf(p0, acc[0][mt][rr]);
                p1 = fmaxf(p1, acc[1][mt][rr]);
            }
        p0 = fmaxf(p0, __shfl_xor(p0, 16, 64));
        p0 = fmaxf(p0, __shfl_xor(p0, 32, 64));
        p1 = fmaxf(p1, __shfl_xor(p1, 16, 64));
        p1 = fmaxf(p1, __shfl_xor(p1, 32, 64));
        if (g == 0) {
            atomicMax(&featsG[p * 256 + nt0 * 16 + rc], __float_as_int(p0));
            atomicMax(&featsG[p * 256 + nt1 * 16 + rc], __float_as_int(p1));
        }
    }
}

// One wave per proposal: 5 dot products of length 256.
__global__ __launch_bounds__(256) void heads_kernel(
    const int* __restrict__ featsG,
    const float* __restrict__ Wc, const float* __restrict__ bc,
    const float* __restrict__ Wr, const float* __restrict__ br,
    float* __restrict__ out, int P)
{
    const int tid  = threadIdx.x;
    const int lane = tid & 63;
    const int p    = blockIdx.x * 4 + (tid >> 6);
    if (p >= P) return;

    const int4 vi = *(const int4*)&featsG[p * 256 + lane * 4];
    float v[4] = {__int_as_float(vi.x), __int_as_float(vi.y),
                  __int_as_float(vi.z), __int_as_float(vi.w)};

    const float4 wc = *(const float4*)&Wc[lane * 4];
    float c  = v[0] * wc.x + v[1] * wc.y + v[2] * wc.z + v[3] * wc.w;
    float r0 = 0.f, r1 = 0.f, r2 = 0.f, r3 = 0.f;
    #pragma unroll
    for (int i = 0; i < 4; ++i) {
        const float4 wr = *(const float4*)&Wr[(lane * 4 + i) * 4];
        r0 = fmaf(v[i], wr.x, r0);
        r1 = fmaf(v[i], wr.y, r1);
        r2 = fmaf(v[i], wr.z, r2);
        r3 = fmaf(v[i], wr.w, r3);
    }
    #pragma unroll
    for (int off = 32; off > 0; off >>= 1) {
        c  += __shfl_xor(c,  off, 64);
        r0 += __shfl_xor(r0, off, 64);
        r1 += __shfl_xor(r1, off, 64);
        r2 += __shfl_xor(r2, off, 64);
        r3 += __shfl_xor(r3, off, 64);
    }
    if (lane == 0) {
        out[p]             = c  + bc[0];
        out[P + p * 4 + 0] = r0 + br[0];
        out[P + p * 4 + 1] = r1 + br[1];
        out[P + p * 4 + 2] = r2 + br[2];
        out[P + p * 4 + 3] = r3 + br[3];
    }
}

extern "C" void kernel_launch(void* const* d_in, const int* in_sizes, int n_in,
                              void* d_out, int out_size, void* d_ws, size_t ws_size,
                              hipStream_t stream)
{
    const float* points    = (const float*)d_in[0];
    const int*   lengths   = (const int*)  d_in[1];
    const float* proposals = (const float*)d_in[2];
    const float* W1 = (const float*)d_in[3];
    const float* b1 = (const float*)d_in[4];
    const float* W2 = (const float*)d_in[5];
    const float* b2 = (const float*)d_in[6];
    const float* W3 = (const float*)d_in[7];
    const float* b3 = (const float*)d_in[8];
    const float* Wc = (const float*)d_in[9];
    const float* bc = (const float*)d_in[10];
    const float* Wr = (const float*)d_in[11];
    const float* br = (const float*)d_in[12];
    float* out = (float*)d_out;

    const int P = in_sizes[1];              // 2048
    const int N = in_sizes[0] / (3 * P);    // 256

    ushort* B2P    = (ushort*)d_ws;                 // 8192 bf16  (16 KB)
    ushort* B3P    = B2P + 8192;                    // 32768 bf16 (64 KB)
    int*    featsG = (int*)((char*)d_ws + 81920);   // P*256 ints (2 MB)

    hipMemsetAsync(featsG, 0, (size_t)P * 256 * sizeof(int), stream);
    pack_weights<<<dim3(128), dim3(256), 0, stream>>>(W2, W3, B2P, B3P);
    refine_wave<<<dim3(P), dim3(256), 0, stream>>>(
        points, lengths, proposals, W1, b1, b2, b3, B2P, B3P, featsG, P, N);
    heads_kernel<<<dim3((P + 3) / 4), dim3(256), 0, stream>>>(
        featsG, Wc, bc, Wr, br, out, P);
}